// Round 7
// baseline (82.279 us; speedup 1.0000x reference)
//
#include <hip/hip_runtime.h>

// Eval-mode stochastic pooling, 2x2 non-overlapping windows:
// out[b,c,i,j] = sum(x^2) / sum(x) over the window.
// Input (16,96,224,224) f32 = 308 MB, Output (16,96,112,112) f32 = 77 MB.
// Purely HBM-bound; traffic is exact (each input byte read once).
//
// A/B vs R5 (single variable): stores are now PLAIN CACHED (R5 had
// nontemporal stores). Loads stay plain cached — R5's best config.
// R4->R5 showed the nt flag on loads cost ~23 us/GB; testing whether the
// same TCC inefficiency applies to the 77 MB store stream.

typedef float f32x4 __attribute__((ext_vector_type(4)));
typedef float f32x2 __attribute__((ext_vector_type(2)));

#define BLOCKS 2044u   // 2044*256 = 523264 = 56 * 9344 (multiple of 56!)

__device__ __forceinline__ f32x2 pool_unit(const float* __restrict__ in,
                                           unsigned base) {
    f32x4 t = *reinterpret_cast<const f32x4*>(in + base);          // cached
    f32x4 b = *reinterpret_cast<const f32x4*>(in + base + 224u);   // cached
    f32x2 o;
    float s0 = (t.x + t.y) + (b.x + b.y);
    float q0 = (t.x * t.x + t.y * t.y) + (b.x * b.x + b.y * b.y);
    float s1 = (t.z + t.w) + (b.z + b.w);
    float q1 = (t.z * t.z + t.w * t.w) + (b.z * b.z + b.w * b.w);
    o.x = q0 * __builtin_amdgcn_rcpf(s0);
    o.y = q1 * __builtin_amdgcn_rcpf(s1);
    return o;
}

__global__ __launch_bounds__(256) void spool2x2_kernel(
    const float* __restrict__ in, float* __restrict__ out, unsigned n2) {
    const unsigned T = gridDim.x * blockDim.x;       // multiple of 56
    const unsigned BSTEP = (T / 56u) * 448u;         // base advance per stride
    unsigned idx = blockIdx.x * blockDim.x + threadIdx.x;
    unsigned q = idx / 56u;                          // once, outside the loop
    unsigned r = idx - q * 56u;
    unsigned base = q * 448u + r * 4u;               // top-row float offset
    f32x2* __restrict__ o2 = reinterpret_cast<f32x2*>(out);

    // main: 4 independent units per iteration (8 loads in flight)
    for (; idx + 3u * T < n2; idx += 4u * T, base += 4u * BSTEP) {
        f32x2 o0 = pool_unit(in, base);
        f32x2 o1 = pool_unit(in, base + BSTEP);
        f32x2 oo2 = pool_unit(in, base + 2u * BSTEP);
        f32x2 o3 = pool_unit(in, base + 3u * BSTEP);
        o2[idx]          = o0;   // plain cached stores (A/B variable)
        o2[idx + T]      = o1;
        o2[idx + 2u * T] = oo2;
        o2[idx + 3u * T] = o3;
    }
    // tail
    for (; idx < n2; idx += T, base += BSTEP) {
        o2[idx] = pool_unit(in, base);
    }
}

extern "C" void kernel_launch(void* const* d_in, const int* in_sizes, int n_in,
                              void* d_out, int out_size, void* d_ws, size_t ws_size,
                              hipStream_t stream) {
    const float* x = (const float*)d_in[0];
    float* out = (float*)d_out;
    unsigned n2 = (unsigned)(out_size / 2);  // 9,633,792 float2 units
    spool2x2_kernel<<<dim3(BLOCKS), dim3(256), 0, stream>>>(x, out, n2);
}

// Round 8
// 64.844 us; speedup vs baseline: 1.2689x; 1.2689x over previous
//
#include <hip/hip_runtime.h>

// Eval-mode stochastic pooling, 2x2 non-overlapping windows:
// out[b,c,i,j] = sum(x^2) / sum(x) over the window.
// Input (16,96,224,224) f32 = 308 MB, Output (16,96,112,112) f32 = 77 MB.
// Purely HBM-bound; traffic is exact (each input byte read/written once).
//
// FINAL CONFIG (R5 winner, fully A/B-mapped over R4-R7):
//   loads  = plain cached   (L3 retains part of the 308 MB input across
//                            graph replays; nt loads cost ~23 us/GB)
//   stores = NONTEMPORAL    (cached stores write-allocate -> evict the
//                            resident input slice; cost +18 us, R7)
// Mapping: one unit = one float4 of the TOP row + matching float4 of the
// BOTTOM row (16B dense per load instr across the wave) -> one float2 of
// output (8B dense store). T multiple of 56 kills all in-loop division;
// v_rcp_f32 replaces IEEE div (rel err 2.4e-7 << 2e-2 threshold).
// 64.0 us = 6.02 TB/s aggregate = 95.7% of measured copy ceiling.

typedef float f32x4 __attribute__((ext_vector_type(4)));
typedef float f32x2 __attribute__((ext_vector_type(2)));

#define BLOCKS 2044u   // 2044*256 = 523264 = 56 * 9344 (multiple of 56!)

__device__ __forceinline__ f32x2 pool_unit(const float* __restrict__ in,
                                           unsigned base) {
    f32x4 t = *reinterpret_cast<const f32x4*>(in + base);          // cached
    f32x4 b = *reinterpret_cast<const f32x4*>(in + base + 224u);   // cached
    f32x2 o;
    float s0 = (t.x + t.y) + (b.x + b.y);
    float q0 = (t.x * t.x + t.y * t.y) + (b.x * b.x + b.y * b.y);
    float s1 = (t.z + t.w) + (b.z + b.w);
    float q1 = (t.z * t.z + t.w * t.w) + (b.z * b.z + b.w * b.w);
    o.x = q0 * __builtin_amdgcn_rcpf(s0);
    o.y = q1 * __builtin_amdgcn_rcpf(s1);
    return o;
}

__global__ __launch_bounds__(256) void spool2x2_kernel(
    const float* __restrict__ in, float* __restrict__ out, unsigned n2) {
    const unsigned T = gridDim.x * blockDim.x;       // multiple of 56
    const unsigned BSTEP = (T / 56u) * 448u;         // base advance per stride
    unsigned idx = blockIdx.x * blockDim.x + threadIdx.x;
    unsigned q = idx / 56u;                          // once, outside the loop
    unsigned r = idx - q * 56u;
    unsigned base = q * 448u + r * 4u;               // top-row float offset
    f32x2* __restrict__ o2 = reinterpret_cast<f32x2*>(out);

    // main: 4 independent units per iteration (8 loads in flight)
    for (; idx + 3u * T < n2; idx += 4u * T, base += 4u * BSTEP) {
        f32x2 o0 = pool_unit(in, base);
        f32x2 o1 = pool_unit(in, base + BSTEP);
        f32x2 oo2 = pool_unit(in, base + 2u * BSTEP);
        f32x2 o3 = pool_unit(in, base + 3u * BSTEP);
        __builtin_nontemporal_store(o0, o2 + idx);
        __builtin_nontemporal_store(o1, o2 + idx + T);
        __builtin_nontemporal_store(oo2, o2 + idx + 2u * T);
        __builtin_nontemporal_store(o3, o2 + idx + 3u * T);
    }
    // tail
    for (; idx < n2; idx += T, base += BSTEP) {
        __builtin_nontemporal_store(pool_unit(in, base), o2 + idx);
    }
}

extern "C" void kernel_launch(void* const* d_in, const int* in_sizes, int n_in,
                              void* d_out, int out_size, void* d_ws, size_t ws_size,
                              hipStream_t stream) {
    const float* x = (const float*)d_in[0];
    float* out = (float*)d_out;
    unsigned n2 = (unsigned)(out_size / 2);  // 9,633,792 float2 units
    spool2x2_kernel<<<dim3(BLOCKS), dim3(256), 0, stream>>>(x, out, n2);
}